// Round 8
// baseline (375.162 us; speedup 1.0000x reference)
//
#include <hip/hip_runtime.h>
#include <stdint.h>

#define NODES 50000
#define D 256
#define MP 50048   // rows padded to multiple of 64
#define NBUCK 196  // buckets of 256 nodes: dst>>8
#define CAP 10240  // per-bucket capacity in ebufT (mean 8163, sigma 90 -> 23 sigma margin)
#define EPB 4096   // edges per block in partA
#define HS_LD 264  // fused-gemm LDS row stride in shorts (256 + 8 pad -> low-way conflicts)
#define CAST_BLOCKS 12500  // NODES*D/4/256
#define AGG_BLOCKS 2048    // fully co-resident at <=64 VGPR: 8 blocks/CU x 256 CU
// 7 nodes per wave (ceil(50000/8192)), float4 value accumulators a0..a6

typedef short bf16x8 __attribute__((ext_vector_type(8)));
typedef float f32x4 __attribute__((ext_vector_type(4)));

__device__ inline unsigned short f2b(float f) {
    unsigned int u = __float_as_uint(f);
    unsigned int r = (u + 0x7fffu + ((u >> 16) & 1u)) >> 16;  // RNE
    return (unsigned short)r;
}

// edge_index dtype auto-detect: reference says int64; harness may deliver int32.
__device__ inline bool ei_is64(const int* ei) {
    return (ei[1] | ei[3] | ei[5] | ei[7]) == 0;
}
__device__ inline int ei_get(const int* __restrict__ ei, long long pos, bool is64) {
    return is64 ? ei[2 * pos] : ei[(int)pos];
}

// ---------------- prep: cast x -> bf16, zero bcnt, offs2 sentinel, pack W1/W2 ----------------
// pack layout: chunk u = (ks*16 + nt)*64 + lane holds B[k = ks*32 + (lane>>4)*8 + j][n = nt*16 + (lane&15)]
__global__ __launch_bounds__(256) void prep_kernel(const float* __restrict__ x,
                                                   unsigned short* __restrict__ xb,
                                                   int* __restrict__ bcnt,
                                                   const float* __restrict__ W1,
                                                   const float* __restrict__ W2,
                                                   unsigned short* __restrict__ P1,
                                                   unsigned short* __restrict__ P2,
                                                   int* __restrict__ offs2, int E) {
    int blk = blockIdx.x;
    if (blk < CAST_BLOCKS) {
        if (blk == 0 && threadIdx.x < NBUCK) bcnt[threadIdx.x] = 0;
        if (blk == 0 && threadIdx.x == 0) offs2[NODES * 8] = E;  // sentinel: end of (49999, chunk 7)
        int t = blk * 256 + threadIdx.x;  // one thread per 4 floats
        float4 v = ((const float4*)x)[t];
        unsigned int lo = (unsigned int)f2b(v.x) | ((unsigned int)f2b(v.y) << 16);
        unsigned int hi = (unsigned int)f2b(v.z) | ((unsigned int)f2b(v.w) << 16);
        ((uint2*)xb)[t] = make_uint2(lo, hi);
    } else {
        int t = (blk - CAST_BLOCKS) * 256 + threadIdx.x;  // 0..16383
        const float* W = (t < 8192) ? W1 : W2;
        unsigned short* P = (t < 8192) ? P1 : P2;
        int u = t & 8191;
        int lane = u & 63, nt = (u >> 6) & 15, s = u >> 10;
        int q = lane >> 4, n = nt * 16 + (lane & 15);
        int kbase = s * 32 + q * 8;
#pragma unroll
        for (int j = 0; j < 8; j++) P[u * 8 + j] = f2b(W[(kbase + j) * D + n]);
    }
}

// ---------------- Pass A: partition edges into 196 dst-buckets ----------------
// Staged through LDS so global writes are bucket-contiguous runs instead of 1.6M
// scattered 4B stores. word layout in stage: bucket<<24 | (dst&255)<<16 | src;
// ebufT stores the low 24 bits only (partB unchanged).
__global__ __launch_bounds__(256) void partA_kernel(const int* __restrict__ ei, int E,
                                                    int* __restrict__ bcnt,
                                                    unsigned int* __restrict__ ebufT) {
    __shared__ int cnt[256];
    __shared__ int incl[256];   // inclusive prefix of cnt
    __shared__ int lcur[256];   // running cursor (starts at exclusive prefix)
    __shared__ int gbase[256];
    __shared__ unsigned int stage[EPB];  // 16 KB
    bool is64 = ei_is64(ei);
    int tid = threadIdx.x;
    cnt[tid] = 0;
    __syncthreads();
    long long pairBase = ((long long)blockIdx.x * EPB) >> 1;
    unsigned int w[16];
    int bk[16];
#pragma unroll
    for (int r = 0; r < 8; r++) {
        long long pp = pairBase + (long long)r * 256 + tid;
        long long e0 = pp * 2;
        int s0 = 0, s1 = 0, d0 = 0, d1 = 0;
        bool v1 = (e0 + 1 < E), v0 = (e0 < E);
        if (v1) {
            if (is64) {
                uint4 sv = *(const uint4*)(ei + 4 * pp);
                uint4 dv = *(const uint4*)(ei + (size_t)2 * E + 4 * pp);
                s0 = (int)sv.x; s1 = (int)sv.z; d0 = (int)dv.x; d1 = (int)dv.z;
            } else {
                uint2 sv = *(const uint2*)(ei + 2 * pp);
                uint2 dv = *(const uint2*)(ei + (size_t)E + 2 * pp);
                s0 = (int)sv.x; s1 = (int)sv.y; d0 = (int)dv.x; d1 = (int)dv.y;
            }
        } else if (v0) {
            s0 = ei_get(ei, e0, is64);
            d0 = ei_get(ei, (long long)E + e0, is64);
        }
        bk[2 * r] = v0 ? (d0 >> 8) : 255;      // 255 = dummy bucket (> NBUCK)
        bk[2 * r + 1] = v1 ? (d1 >> 8) : 255;
        w[2 * r] = ((unsigned int)bk[2 * r] << 24) |
                   ((unsigned int)(d0 & 255) << 16) | (unsigned int)s0;
        w[2 * r + 1] = ((unsigned int)bk[2 * r + 1] << 24) |
                       ((unsigned int)(d1 & 255) << 16) | (unsigned int)s1;
        atomicAdd(&cnt[bk[2 * r]], 1);
        atomicAdd(&cnt[bk[2 * r + 1]], 1);
    }
    __syncthreads();
    int c = cnt[tid];
    incl[tid] = c;
    __syncthreads();
    for (int off = 1; off < 256; off <<= 1) {
        int xv = (tid >= off) ? incl[tid - off] : 0;
        __syncthreads();
        incl[tid] += xv;
        __syncthreads();
    }
    if (tid < NBUCK && c > 0) gbase[tid] = atomicAdd(&bcnt[tid], c);
    lcur[tid] = incl[tid] - c;  // exclusive prefix
    __syncthreads();
#pragma unroll
    for (int r = 0; r < 16; r++) {
        int p = atomicAdd(&lcur[bk[r]], 1);
        stage[p] = w[r];
    }
    __syncthreads();
    for (int i = tid; i < EPB; i += 256) {
        unsigned int u = stage[i];
        int b = u >> 24;
        if (b < NBUCK) {
            int slot = gbase[b] + (i - (incl[b] - cnt[b]));
            ebufT[(size_t)b * CAP + slot] = u & 0x00FFFFFFu;
        }
    }
}

// ---------------- Pass B: per-(node, src-chunk) counting sort + offs2 emit ----------------
// Edges within each node's range are ordered by src>>13 (8192-node chunks = 4 MB bf16
// slices). offs2[node*8+c] = global start of (node, chunk c); end = offs2[node*8+c+1]
// (bucket bases are contiguous, so this holds across node boundaries too).
__global__ __launch_bounds__(1024) void partB_kernel(const int* __restrict__ bcnt,
                                                     const unsigned int* __restrict__ ebufT,
                                                     int* __restrict__ offs2,
                                                     int* __restrict__ ebuf) {
    __shared__ int sb[256];
    __shared__ int ncnt[2048];   // [node-in-bucket][src chunk 0..7]
    __shared__ int ncur[2048];
    __shared__ int nexcl[256];
    int b = blockIdx.x, tid = threadIdx.x;
    if (tid < 256) sb[tid] = (tid < NBUCK) ? bcnt[tid] : 0;
    for (int i = tid; i < 2048; i += 1024) ncnt[i] = 0;
    __syncthreads();
    for (int off = 1; off < 256; off <<= 1) {
        int xv = 0;
        if (tid < 256 && tid >= off) xv = sb[tid - off];
        __syncthreads();
        if (tid < 256) sb[tid] += xv;
        __syncthreads();
    }
    int n = bcnt[b];
    int base = sb[b] - n;  // exclusive prefix over buckets
    const unsigned int* reg = ebufT + (size_t)b * CAP;
    for (int i = tid; i < n; i += 1024) {
        unsigned int w = reg[i];
        atomicAdd(&ncnt[((w >> 16) << 3) | ((w & 0xffffu) >> 13)], 1);
    }
    __syncthreads();
    if (tid < 256) {
        int s = 0;
#pragma unroll
        for (int c = 0; c < 8; c++) s += ncnt[tid * 8 + c];
        nexcl[tid] = s;
    }
    __syncthreads();
    for (int off = 1; off < 256; off <<= 1) {
        int xv = 0;
        if (tid < 256 && tid >= off) xv = nexcl[tid - off];
        __syncthreads();
        if (tid < 256) nexcl[tid] += xv;
        __syncthreads();
    }
    if (tid < 256) {
        int s = 0;
#pragma unroll
        for (int c = 0; c < 8; c++) s += ncnt[tid * 8 + c];
        int excl = nexcl[tid] - s;
        int node = b * 256 + tid;
        int run = excl;
#pragma unroll
        for (int c = 0; c < 8; c++) {
            ncur[tid * 8 + c] = run;
            if (node < NODES) offs2[node * 8 + c] = base + run;
            run += ncnt[tid * 8 + c];
        }
    }
    __syncthreads();
    for (int i = tid; i < n; i += 1024) {
        unsigned int w = reg[i];
        int p = atomicAdd(&ncur[((w >> 16) << 3) | ((w & 0xffffu) >> 13)], 1);
        ebuf[base + p] = (int)(w & 0xffffu);
    }
}

// ---------------- aggregation: PERSISTENT era-based gather, slim register budget ----------------
// 2048 blocks x 4 waves = 8192 waves co-resident (launch_bounds(256,8): 64-VGPR cap).
// r5/r7 spilled the 28 accumulator floats (VGPR=32 + 60 MB scratch writes): under the
// 64-cap the allocator spills longest-live/lowest-density values = the accumulators.
// This version shrinks the working set to fit: float4 VALUE accumulators (no arrays),
// 2-deep inner pipeline (era segments average 4 edges; 4-deep temps were ~20 regs),
// self-term moved to epilogue (xb is L3-resident by then). Budget ~54 < 64.
// Era c: whole GPU gathers from one 3.2 MB xb slice -> per-XCD L2 -> FETCH floor
// 8 x 25.6 = 205 MB (era scheme measured ~238 MB vs 354 MB without).
__device__ inline float4 upk2v(uint2 w, float4 a) {
    a.x += __uint_as_float(w.x << 16);
    a.y += __uint_as_float(w.x & 0xffff0000u);
    a.z += __uint_as_float(w.y << 16);
    a.w += __uint_as_float(w.y & 0xffff0000u);
    return a;
}

__global__ __launch_bounds__(256, 8) void agg_kernel(const unsigned short* __restrict__ xb,
                                                     const int* __restrict__ offs2,
                                                     const int* __restrict__ ebuf,
                                                     const float* __restrict__ eps,
                                                     unsigned short* __restrict__ h0) {
    int W = (blockIdx.x << 2) | (threadIdx.x >> 6);  // global wave 0..8191
    int lane = threadIdx.x & 63;
    const unsigned short* colBase = xb + lane * 4;   // lane owns cols 4l..4l+3
    float4 a0 = {0, 0, 0, 0}, a1 = {0, 0, 0, 0}, a2 = {0, 0, 0, 0};
    float4 a3 = {0, 0, 0, 0}, a4 = {0, 0, 0, 0}, a5 = {0, 0, 0, 0};
    float4 a6 = {0, 0, 0, 0};
    bool has6 = (W < NODES - 6 * 8192);  // W < 848

    for (int c = 0; c < 8; ++c) {
        // T is a literal; ACC is a named float4 (pure value flow -> registers)
#define ERA_SEG(T, ACC, GUARD)                                                 \
        if (GUARD) {                                                           \
            int node = W + ((T) << 13);                                        \
            int beg = offs2[node * 8 + c];                                     \
            int end = offs2[node * 8 + c + 1];                                 \
            int j = beg;                                                       \
            for (; j + 2 <= end; j += 2) {                                     \
                int i0 = ebuf[j], i1 = ebuf[j + 1];                            \
                uint2 g0 = *(const uint2*)(colBase + (size_t)i0 * D);          \
                uint2 g1 = *(const uint2*)(colBase + (size_t)i1 * D);          \
                ACC = upk2v(g0, ACC);                                          \
                ACC = upk2v(g1, ACC);                                          \
            }                                                                  \
            if (j < end) {                                                     \
                uint2 g = *(const uint2*)(colBase + (size_t)ebuf[j] * D);      \
                ACC = upk2v(g, ACC);                                           \
            }                                                                  \
        }
        ERA_SEG(0, a0, true)
        ERA_SEG(1, a1, true)
        ERA_SEG(2, a2, true)
        ERA_SEG(3, a3, true)
        ERA_SEG(4, a4, true)
        ERA_SEG(5, a5, true)
        ERA_SEG(6, a6, has6)
#undef ERA_SEG
    }

    // epilogue: self term (xb row is L3-resident after the eras) + pack + store
    float scale = 1.0f + eps[0];
#define WRITE_T(T, ACC, GUARD)                                                 \
    if (GUARD) {                                                               \
        int node = W + ((T) << 13);                                            \
        uint2 v = *(const uint2*)(colBase + (size_t)node * D);                 \
        ACC.x += scale * __uint_as_float(v.x << 16);                           \
        ACC.y += scale * __uint_as_float(v.x & 0xffff0000u);                   \
        ACC.z += scale * __uint_as_float(v.y << 16);                           \
        ACC.w += scale * __uint_as_float(v.y & 0xffff0000u);                   \
        unsigned long long packed =                                            \
            (unsigned long long)((unsigned int)f2b(ACC.x) |                    \
                                 ((unsigned int)f2b(ACC.y) << 16)) |           \
            ((unsigned long long)((unsigned int)f2b(ACC.z) |                   \
                                  ((unsigned int)f2b(ACC.w) << 16))            \
             << 32);                                                           \
        *(unsigned long long*)(h0 + (size_t)node * D + lane * 4) = packed;     \
    }
    WRITE_T(0, a0, true)
    WRITE_T(1, a1, true)
    WRITE_T(2, a2, true)
    WRITE_T(3, a3, true)
    WRITE_T(4, a4, true)
    WRITE_T(5, a5, true)
    WRITE_T(6, a6, has6)
#undef WRITE_T
}

// ---------------- fused MLP: out = relu(A@W1+b1)@W2 + b2 ----------------
// block = 4 waves, 64 rows; stage 1 -> bf16 tile in padded LDS; stage 2 -> fp32 out.
__global__ __launch_bounds__(256) void gemm_fused_kernel(const unsigned short* __restrict__ A,
                                                         const unsigned short* __restrict__ P1,
                                                         const float* __restrict__ b1,
                                                         const unsigned short* __restrict__ P2,
                                                         const float* __restrict__ b2,
                                                         float* __restrict__ out, int Mvalid) {
    __shared__ unsigned short hs[64 * HS_LD];  // 33 KB
    int wv = threadIdx.x >> 6;  // n 64-tile, 0..3
    int lane = threadIdx.x & 63;
    int quad = lane >> 4, l16 = lane & 15;
    int mBase = blockIdx.x * 64;
    const bf16x8* B1v = (const bf16x8*)P1;
    const bf16x8* B2v = (const bf16x8*)P2;

    // ---- stage 1: h = relu(A@W1+b1) -> LDS (bf16) ----
    {
        f32x4 acc[4][4] = {};
#pragma unroll
        for (int ks = 0; ks < 8; ks++) {
            bf16x8 af[4], bf[4];
#pragma unroll
            for (int mi = 0; mi < 4; mi++) {
                int row = mBase + mi * 16 + l16;
                af[mi] = *(const bf16x8*)(A + (size_t)row * D + ks * 32 + quad * 8);
            }
#pragma unroll
            for (int ni = 0; ni < 4; ni++) bf[ni] = B1v[(ks * 16 + wv * 4 + ni) * 64 + lane];
#pragma unroll
            for (int mi = 0; mi < 4; mi++)
#pragma unroll
                for (int ni = 0; ni < 4; ni++)
                    acc[mi][ni] = __builtin_amdgcn_mfma_f32_16x16x32_bf16(af[mi], bf[ni],
                                                                          acc[mi][ni], 0, 0, 0);
        }
#pragma unroll
        for (int mi = 0; mi < 4; mi++)
#pragma unroll
            for (int ni = 0; ni < 4; ni++) {
                int col = wv * 64 + ni * 16 + l16;
                float bs = b1[col];
#pragma unroll
                for (int r = 0; r < 4; r++) {
                    int rl = mi * 16 + quad * 4 + r;
                    hs[rl * HS_LD + col] = f2b(fmaxf(acc[mi][ni][r] + bs, 0.0f));
                }
            }
    }
    __syncthreads();

    // ---- stage 2: out = h@W2 + b2 (A-frags from LDS) ----
    f32x4 acc[4][4] = {};
#pragma unroll
    for (int ks = 0; ks < 8; ks++) {
        bf16x8 af[4], bf[4];
#pragma unroll
        for (int mi = 0; mi < 4; mi++)
            af[mi] = *(const bf16x8*)(hs + (mi * 16 + l16) * HS_LD + ks * 32 + quad * 8);
#pragma unroll
        for (int ni = 0; ni < 4; ni++) bf[ni] = B2v[(ks * 16 + wv * 4 + ni) * 64 + lane];
#pragma unroll
        for (int mi = 0; mi < 4; mi++)
#pragma unroll
            for (int ni = 0; ni < 4; ni++)
                acc[mi][ni] =
                    __builtin_amdgcn_mfma_f32_16x16x32_bf16(af[mi], bf[ni], acc[mi][ni], 0, 0, 0);
    }
#pragma unroll
    for (int mi = 0; mi < 4; mi++)
#pragma unroll
        for (int ni = 0; ni < 4; ni++) {
            int col = wv * 64 + ni * 16 + l16;
            float bs = b2[col];
#pragma unroll
            for (int r = 0; r < 4; r++) {
                int row = mBase + mi * 16 + quad * 4 + r;
                if (row < Mvalid) out[(size_t)row * D + col] = acc[mi][ni][r] + bs;
            }
        }
}

extern "C" void kernel_launch(void* const* d_in, const int* in_sizes, int n_in,
                              void* d_out, int out_size, void* d_ws, size_t ws_size,
                              hipStream_t stream) {
    const float* x = (const float*)d_in[0];
    const int* ei = (const int*)d_in[1];
    // d_in[2] = edge_attr, unused by forward
    const float* W1 = (const float*)d_in[3];
    const float* b1 = (const float*)d_in[4];
    const float* W2 = (const float*)d_in[5];
    const float* b2 = (const float*)d_in[6];
    const float* eps = (const float*)d_in[7];
    int E = in_sizes[1] / 2;  // 1,600,000

    char* p = (char*)d_ws;
    auto alloc = [&](size_t bytes) {
        char* r = p;
        p += (bytes + 255) & ~(size_t)255;
        return r;
    };
    unsigned short* xb = (unsigned short*)alloc((size_t)MP * D * 2);
    unsigned short* h0 = (unsigned short*)alloc((size_t)MP * D * 2);
    unsigned short* P1 = (unsigned short*)alloc(8192 * 8 * 2);
    unsigned short* P2 = (unsigned short*)alloc(8192 * 8 * 2);
    int* bcnt = (int*)alloc((size_t)NBUCK * 4);
    int* offs2 = (int*)alloc((size_t)(NODES * 8 + 1) * 4);
    int* ebuf = (int*)alloc((size_t)E * 4);
    unsigned int* ebufT = (unsigned int*)alloc((size_t)NBUCK * CAP * 4);

    prep_kernel<<<CAST_BLOCKS + 64, 256, 0, stream>>>(x, xb, bcnt, W1, W2, P1, P2, offs2, E);
    partA_kernel<<<(E + EPB - 1) / EPB, 256, 0, stream>>>(ei, E, bcnt, ebufT);
    partB_kernel<<<NBUCK, 1024, 0, stream>>>(bcnt, ebufT, offs2, ebuf);
    agg_kernel<<<AGG_BLOCKS, 256, 0, stream>>>(xb, offs2, ebuf, eps, h0);
    gemm_fused_kernel<<<MP / 64, 256, 0, stream>>>(h0, P1, b1, P2, b2, (float*)d_out, NODES);
}

// Round 10
// 359.522 us; speedup vs baseline: 1.0435x; 1.0435x over previous
//
#include <hip/hip_runtime.h>
#include <stdint.h>

#define NODES 50000
#define D 256
#define MP 50048   // rows padded to multiple of 64
#define NBUCK 196  // buckets of 256 nodes: dst>>8
#define CAP 10240  // per-bucket capacity in ebufT (mean 8163, sigma 90 -> 23 sigma margin)
#define EPB 4096   // edges per block in partA
#define HS_LD 264  // fused-gemm LDS row stride in shorts (256 + 8 pad -> low-way conflicts)
#define CAST_BLOCKS 12500  // NODES*D/4/256
#define NCHUNK 16  // src chunks of 4096 nodes = 1.6 MB bf16 each (r8 model: L2-miss-stream
                   // bound at 3.44 TB/s; finer chunks shrink the skew window under 4 MB L2)

typedef short bf16x8 __attribute__((ext_vector_type(8)));
typedef float f32x4 __attribute__((ext_vector_type(4)));

__device__ inline unsigned short f2b(float f) {
    unsigned int u = __float_as_uint(f);
    unsigned int r = (u + 0x7fffu + ((u >> 16) & 1u)) >> 16;  // RNE
    return (unsigned short)r;
}

// edge_index dtype auto-detect: reference says int64; harness may deliver int32.
__device__ inline bool ei_is64(const int* ei) {
    return (ei[1] | ei[3] | ei[5] | ei[7]) == 0;
}
__device__ inline int ei_get(const int* __restrict__ ei, long long pos, bool is64) {
    return is64 ? ei[2 * pos] : ei[(int)pos];
}

// ---------------- prep: cast x -> bf16, zero bcnt, offs[NODES]=E, pack W1/W2 ----------------
// pack layout: chunk u = (ks*16 + nt)*64 + lane holds B[k = ks*32 + (lane>>4)*8 + j][n = nt*16 + (lane&15)]
__global__ __launch_bounds__(256) void prep_kernel(const float* __restrict__ x,
                                                   unsigned short* __restrict__ xb,
                                                   int* __restrict__ bcnt,
                                                   const float* __restrict__ W1,
                                                   const float* __restrict__ W2,
                                                   unsigned short* __restrict__ P1,
                                                   unsigned short* __restrict__ P2,
                                                   int* __restrict__ offs, int E) {
    int blk = blockIdx.x;
    if (blk < CAST_BLOCKS) {
        if (blk == 0 && threadIdx.x < NBUCK) bcnt[threadIdx.x] = 0;
        if (blk == 0 && threadIdx.x == 0) offs[NODES] = E;
        int t = blk * 256 + threadIdx.x;  // one thread per 4 floats
        float4 v = ((const float4*)x)[t];
        unsigned int lo = (unsigned int)f2b(v.x) | ((unsigned int)f2b(v.y) << 16);
        unsigned int hi = (unsigned int)f2b(v.z) | ((unsigned int)f2b(v.w) << 16);
        ((uint2*)xb)[t] = make_uint2(lo, hi);
    } else {
        int t = (blk - CAST_BLOCKS) * 256 + threadIdx.x;  // 0..16383
        const float* W = (t < 8192) ? W1 : W2;
        unsigned short* P = (t < 8192) ? P1 : P2;
        int u = t & 8191;
        int lane = u & 63, nt = (u >> 6) & 15, s = u >> 10;
        int q = lane >> 4, n = nt * 16 + (lane & 15);
        int kbase = s * 32 + q * 8;
#pragma unroll
        for (int j = 0; j < 8; j++) P[u * 8 + j] = f2b(W[(kbase + j) * D + n]);
    }
}

// ---------------- Pass A: partition edges into 196 dst-buckets ----------------
// Staged through LDS so global writes are bucket-contiguous runs instead of 1.6M
// scattered 4B stores. word layout in stage: bucket<<24 | (dst&255)<<16 | src;
// ebufT stores the low 24 bits only (partB unchanged).
__global__ __launch_bounds__(256) void partA_kernel(const int* __restrict__ ei, int E,
                                                    int* __restrict__ bcnt,
                                                    unsigned int* __restrict__ ebufT) {
    __shared__ int cnt[256];
    __shared__ int incl[256];   // inclusive prefix of cnt
    __shared__ int lcur[256];   // running cursor (starts at exclusive prefix)
    __shared__ int gbase[256];
    __shared__ unsigned int stage[EPB];  // 16 KB
    bool is64 = ei_is64(ei);
    int tid = threadIdx.x;
    cnt[tid] = 0;
    __syncthreads();
    long long pairBase = ((long long)blockIdx.x * EPB) >> 1;
    unsigned int w[16];
    int bk[16];
#pragma unroll
    for (int r = 0; r < 8; r++) {
        long long pp = pairBase + (long long)r * 256 + tid;
        long long e0 = pp * 2;
        int s0 = 0, s1 = 0, d0 = 0, d1 = 0;
        bool v1 = (e0 + 1 < E), v0 = (e0 < E);
        if (v1) {
            if (is64) {
                uint4 sv = *(const uint4*)(ei + 4 * pp);
                uint4 dv = *(const uint4*)(ei + (size_t)2 * E + 4 * pp);
                s0 = (int)sv.x; s1 = (int)sv.z; d0 = (int)dv.x; d1 = (int)dv.z;
            } else {
                uint2 sv = *(const uint2*)(ei + 2 * pp);
                uint2 dv = *(const uint2*)(ei + (size_t)E + 2 * pp);
                s0 = (int)sv.x; s1 = (int)sv.y; d0 = (int)dv.x; d1 = (int)dv.y;
            }
        } else if (v0) {
            s0 = ei_get(ei, e0, is64);
            d0 = ei_get(ei, (long long)E + e0, is64);
        }
        bk[2 * r] = v0 ? (d0 >> 8) : 255;      // 255 = dummy bucket (> NBUCK)
        bk[2 * r + 1] = v1 ? (d1 >> 8) : 255;
        w[2 * r] = ((unsigned int)bk[2 * r] << 24) |
                   ((unsigned int)(d0 & 255) << 16) | (unsigned int)s0;
        w[2 * r + 1] = ((unsigned int)bk[2 * r + 1] << 24) |
                       ((unsigned int)(d1 & 255) << 16) | (unsigned int)s1;
        atomicAdd(&cnt[bk[2 * r]], 1);
        atomicAdd(&cnt[bk[2 * r + 1]], 1);
    }
    __syncthreads();
    int c = cnt[tid];
    incl[tid] = c;
    __syncthreads();
    for (int off = 1; off < 256; off <<= 1) {
        int xv = (tid >= off) ? incl[tid - off] : 0;
        __syncthreads();
        incl[tid] += xv;
        __syncthreads();
    }
    if (tid < NBUCK && c > 0) gbase[tid] = atomicAdd(&bcnt[tid], c);
    lcur[tid] = incl[tid] - c;  // exclusive prefix
    __syncthreads();
#pragma unroll
    for (int r = 0; r < 16; r++) {
        int p = atomicAdd(&lcur[bk[r]], 1);
        stage[p] = w[r];
    }
    __syncthreads();
    for (int i = tid; i < EPB; i += 256) {
        unsigned int u = stage[i];
        int b = u >> 24;
        if (b < NBUCK) {
            int slot = gbase[b] + (i - (incl[b] - cnt[b]));
            ebufT[(size_t)b * CAP + slot] = u & 0x00FFFFFFu;
        }
    }
}

// ---------------- Pass B: per-(node, src-chunk) counting sort, 16 chunks ----------------
// Edges within each node's range are ordered by src>>12 (4096-node chunks = 1.6 MB bf16
// slices). agg walks each node's range straight through (no per-segment control flow);
// chunk order only shapes the data stream so concurrently-resident waves' gather
// footprint (2-3 chunks of skew) fits the 4 MB per-XCD L2.
__global__ __launch_bounds__(1024) void partB_kernel(const int* __restrict__ bcnt,
                                                     const unsigned int* __restrict__ ebufT,
                                                     int* __restrict__ offs,
                                                     int* __restrict__ ebuf) {
    __shared__ int sb[256];
    __shared__ int ncnt[256 * NCHUNK];   // [node-in-bucket][src chunk]
    __shared__ int ncur[256 * NCHUNK];
    __shared__ int nexcl[256];
    int b = blockIdx.x, tid = threadIdx.x;
    if (tid < 256) sb[tid] = (tid < NBUCK) ? bcnt[tid] : 0;
    for (int i = tid; i < 256 * NCHUNK; i += 1024) ncnt[i] = 0;
    __syncthreads();
    for (int off = 1; off < 256; off <<= 1) {
        int xv = 0;
        if (tid < 256 && tid >= off) xv = sb[tid - off];
        __syncthreads();
        if (tid < 256) sb[tid] += xv;
        __syncthreads();
    }
    int n = bcnt[b];
    int base = sb[b] - n;  // exclusive prefix over buckets
    const unsigned int* reg = ebufT + (size_t)b * CAP;
    for (int i = tid; i < n; i += 1024) {
        unsigned int w = reg[i];
        atomicAdd(&ncnt[((w >> 16) << 4) | ((w & 0xffffu) >> 12)], 1);
    }
    __syncthreads();
    if (tid < 256) {
        int s = 0;
#pragma unroll
        for (int c = 0; c < NCHUNK; c++) s += ncnt[tid * NCHUNK + c];
        nexcl[tid] = s;
    }
    __syncthreads();
    for (int off = 1; off < 256; off <<= 1) {
        int xv = 0;
        if (tid < 256 && tid >= off) xv = nexcl[tid - off];
        __syncthreads();
        if (tid < 256) nexcl[tid] += xv;
        __syncthreads();
    }
    if (tid < 256) {
        int s = 0;
#pragma unroll
        for (int c = 0; c < NCHUNK; c++) s += ncnt[tid * NCHUNK + c];
        int excl = nexcl[tid] - s;
        int node = b * 256 + tid;
        if (node < NODES) offs[node] = base + excl;
        int run = excl;
#pragma unroll
        for (int c = 0; c < NCHUNK; c++) {
            ncur[tid * NCHUNK + c] = run;
            run += ncnt[tid * NCHUNK + c];
        }
    }
    __syncthreads();
    for (int i = tid; i < n; i += 1024) {
        unsigned int w = reg[i];
        int p = atomicAdd(&ncur[((w >> 16) << 4) | ((w & 0xffffu) >> 12)], 1);
        ebuf[base + p] = (int)(w & 0xffffu);
    }
}

// ---------------- aggregation: single pass, full row, one wave per node ----------------
// r3-proven structure (103 us @ 8-chunk sort). 50000 waves, VGPR~28 -> 8 waves/SIMD.
// Lane owns cols 4l..4l+3 (8B); one wave-instr gathers a full 512B row; 8 loads in
// flight; whole node range walked in one loop (no segment serialization — r8's era
// variant hit the 205 MB fetch floor but lost to latency at 120 us).
// Model: time ~= FETCH / 3.44 TB/s (L2-miss stream ceiling, r3/r8 fits).
__device__ inline void upk2(uint2 w, float* a) {
    a[0] += __uint_as_float(w.x << 16);
    a[1] += __uint_as_float(w.x & 0xffff0000u);
    a[2] += __uint_as_float(w.y << 16);
    a[3] += __uint_as_float(w.y & 0xffff0000u);
}

__global__ __launch_bounds__(256) void agg_kernel(const unsigned short* __restrict__ xb,
                                                  const int* __restrict__ offs,
                                                  const int* __restrict__ ebuf,
                                                  const float* __restrict__ eps,
                                                  unsigned short* __restrict__ h0) {
    int wv = (blockIdx.x * 256 + threadIdx.x) >> 6;
    if (wv >= NODES) return;
    int lane = threadIdx.x & 63;
    const unsigned short* colBase = xb + lane * 4;
    float aa[4] = {0, 0, 0, 0}, bb[4] = {0, 0, 0, 0};
    int beg = offs[wv], end = offs[wv + 1];
    int j = beg;
    for (; j + 8 <= end; j += 8) {
        int idx[8];
        uint2 g[8];
#pragma unroll
        for (int k = 0; k < 8; k++) idx[k] = ebuf[j + k];
#pragma unroll
        for (int k = 0; k < 8; k++) g[k] = *(const uint2*)(colBase + (size_t)idx[k] * D);
#pragma unroll
        for (int k = 0; k < 8; k += 2) {
            upk2(g[k], aa);
            upk2(g[k + 1], bb);
        }
    }
    if (j + 4 <= end) {
        int idx[4];
        uint2 g[4];
#pragma unroll
        for (int k = 0; k < 4; k++) idx[k] = ebuf[j + k];
#pragma unroll
        for (int k = 0; k < 4; k++) g[k] = *(const uint2*)(colBase + (size_t)idx[k] * D);
#pragma unroll
        for (int k = 0; k < 4; k += 2) {
            upk2(g[k], aa);
            upk2(g[k + 1], bb);
        }
        j += 4;
    }
    for (; j < end; ++j) {
        uint2 g = *(const uint2*)(colBase + (size_t)ebuf[j] * D);
        upk2(g, aa);
    }
    float scale = 1.0f + eps[0];
    uint2 v = *(const uint2*)(colBase + (size_t)wv * D);
    aa[0] += scale * __uint_as_float(v.x << 16);
    aa[1] += scale * __uint_as_float(v.x & 0xffff0000u);
    aa[2] += scale * __uint_as_float(v.y << 16);
    aa[3] += scale * __uint_as_float(v.y & 0xffff0000u);
    unsigned int lo = (unsigned int)f2b(aa[0] + bb[0]) | ((unsigned int)f2b(aa[1] + bb[1]) << 16);
    unsigned int hi = (unsigned int)f2b(aa[2] + bb[2]) | ((unsigned int)f2b(aa[3] + bb[3]) << 16);
    *(uint2*)(h0 + (size_t)wv * D + lane * 4) = make_uint2(lo, hi);
}

// ---------------- fused MLP: out = relu(A@W1+b1)@W2 + b2 ----------------
// block = 4 waves, 64 rows; stage 1 -> bf16 tile in padded LDS; stage 2 -> fp32 out.
__global__ __launch_bounds__(256) void gemm_fused_kernel(const unsigned short* __restrict__ A,
                                                         const unsigned short* __restrict__ P1,
                                                         const float* __restrict__ b1,
                                                         const unsigned short* __restrict__ P2,
                                                         const float* __restrict__ b2,
                                                         float* __restrict__ out, int Mvalid) {
    __shared__ unsigned short hs[64 * HS_LD];  // 33 KB
    int wv = threadIdx.x >> 6;  // n 64-tile, 0..3
    int lane = threadIdx.x & 63;
    int quad = lane >> 4, l16 = lane & 15;
    int mBase = blockIdx.x * 64;
    const bf16x8* B1v = (const bf16x8*)P1;
    const bf16x8* B2v = (const bf16x8*)P2;

    // ---- stage 1: h = relu(A@W1+b1) -> LDS (bf16) ----
    {
        f32x4 acc[4][4] = {};
#pragma unroll
        for (int ks = 0; ks < 8; ks++) {
            bf16x8 af[4], bf[4];
#pragma unroll
            for (int mi = 0; mi < 4; mi++) {
                int row = mBase + mi * 16 + l16;
                af[mi] = *(const bf16x8*)(A + (size_t)row * D + ks * 32 + quad * 8);
            }
#pragma unroll
            for (int ni = 0; ni < 4; ni++) bf[ni] = B1v[(ks * 16 + wv * 4 + ni) * 64 + lane];
#pragma unroll
            for (int mi = 0; mi < 4; mi++)
#pragma unroll
                for (int ni = 0; ni < 4; ni++)
                    acc[mi][ni] = __builtin_amdgcn_mfma_f32_16x16x32_bf16(af[mi], bf[ni],
                                                                          acc[mi][ni], 0, 0, 0);
        }
#pragma unroll
        for (int mi = 0; mi < 4; mi++)
#pragma unroll
            for (int ni = 0; ni < 4; ni++) {
                int col = wv * 64 + ni * 16 + l16;
                float bs = b1[col];
#pragma unroll
                for (int r = 0; r < 4; r++) {
                    int rl = mi * 16 + quad * 4 + r;
                    hs[rl * HS_LD + col] = f2b(fmaxf(acc[mi][ni][r] + bs, 0.0f));
                }
            }
    }
    __syncthreads();

    // ---- stage 2: out = h@W2 + b2 (A-frags from LDS) ----
    f32x4 acc[4][4] = {};
#pragma unroll
    for (int ks = 0; ks < 8; ks++) {
        bf16x8 af[4], bf[4];
#pragma unroll
        for (int mi = 0; mi < 4; mi++)
            af[mi] = *(const bf16x8*)(hs + (mi * 16 + l16) * HS_LD + ks * 32 + quad * 8);
#pragma unroll
        for (int ni = 0; ni < 4; ni++) bf[ni] = B2v[(ks * 16 + wv * 4 + ni) * 64 + lane];
#pragma unroll
        for (int mi = 0; mi < 4; mi++)
#pragma unroll
            for (int ni = 0; ni < 4; ni++)
                acc[mi][ni] =
                    __builtin_amdgcn_mfma_f32_16x16x32_bf16(af[mi], bf[ni], acc[mi][ni], 0, 0, 0);
    }
#pragma unroll
    for (int mi = 0; mi < 4; mi++)
#pragma unroll
        for (int ni = 0; ni < 4; ni++) {
            int col = wv * 64 + ni * 16 + l16;
            float bs = b2[col];
#pragma unroll
            for (int r = 0; r < 4; r++) {
                int row = mBase + mi * 16 + quad * 4 + r;
                if (row < Mvalid) out[(size_t)row * D + col] = acc[mi][ni][r] + bs;
            }
        }
}

extern "C" void kernel_launch(void* const* d_in, const int* in_sizes, int n_in,
                              void* d_out, int out_size, void* d_ws, size_t ws_size,
                              hipStream_t stream) {
    const float* x = (const float*)d_in[0];
    const int* ei = (const int*)d_in[1];
    // d_in[2] = edge_attr, unused by forward
    const float* W1 = (const float*)d_in[3];
    const float* b1 = (const float*)d_in[4];
    const float* W2 = (const float*)d_in[5];
    const float* b2 = (const float*)d_in[6];
    const float* eps = (const float*)d_in[7];
    int E = in_sizes[1] / 2;  // 1,600,000

    char* p = (char*)d_ws;
    auto alloc = [&](size_t bytes) {
        char* r = p;
        p += (bytes + 255) & ~(size_t)255;
        return r;
    };
    unsigned short* xb = (unsigned short*)alloc((size_t)MP * D * 2);
    unsigned short* h0 = (unsigned short*)alloc((size_t)MP * D * 2);
    unsigned short* P1 = (unsigned short*)alloc(8192 * 8 * 2);
    unsigned short* P2 = (unsigned short*)alloc(8192 * 8 * 2);
    int* bcnt = (int*)alloc((size_t)NBUCK * 4);
    int* offs = (int*)alloc((size_t)(NODES + 1) * 4);
    int* ebuf = (int*)alloc((size_t)E * 4);
    unsigned int* ebufT = (unsigned int*)alloc((size_t)NBUCK * CAP * 4);

    prep_kernel<<<CAST_BLOCKS + 64, 256, 0, stream>>>(x, xb, bcnt, W1, W2, P1, P2, offs, E);
    partA_kernel<<<(E + EPB - 1) / EPB, 256, 0, stream>>>(ei, E, bcnt, ebufT);
    partB_kernel<<<NBUCK, 1024, 0, stream>>>(bcnt, ebufT, offs, ebuf);
    agg_kernel<<<(NODES + 3) / 4, 256, 0, stream>>>(xb, offs, ebuf, eps, h0);
    gemm_fused_kernel<<<MP / 64, 256, 0, stream>>>(h0, P1, b1, P2, b2, (float*)d_out, NODES);
}